// Round 1
// baseline (711.004 us; speedup 1.0000x reference)
//
#include <hip/hip_runtime.h>

#define CB 64
#define CN 4096
#define CD 256
#define CS 8
#define CH 512

typedef __bf16 bf16_t;
typedef bf16_t bf16x8 __attribute__((ext_vector_type(8)));
typedef float f32x4 __attribute__((ext_vector_type(4)));

__device__ __forceinline__ unsigned short f2bf(float f){
  unsigned int u = __builtin_bit_cast(unsigned int, f);
  u += 0x7FFFu + ((u >> 16) & 1u);
  return (unsigned short)(u >> 16);
}

__device__ __forceinline__ f32x4 mfma16(bf16x8 a, bf16x8 b, f32x4 c){
  return __builtin_amdgcn_mfma_f32_16x16x32_bf16(a, b, c, 0, 0, 0);
}

__device__ __forceinline__ void gl_lds16(const void* g, void* l){
  __builtin_amdgcn_global_load_lds(
      (const __attribute__((address_space(1))) unsigned int*)g,
      (__attribute__((address_space(3))) unsigned int*)l, 16, 0, 0);
}

// ---------------- LN over inputs -> x (bf16, row-major) ----------------
__global__ __launch_bounds__(256) void k_ln(const float* __restrict__ in,
    const float* __restrict__ gw, const float* __restrict__ gb,
    unsigned short* __restrict__ x){
  int blk = blockIdx.x;            // 4096 = 64 b * 64 ntiles
  int b = blk >> 6, nt = blk & 63;
  int wv = threadIdx.x >> 6, l = threadIdx.x & 63;
  const float* base = in + ((size_t)b*CN + (size_t)nt*64) * CD;
  unsigned short* xb = x + ((size_t)b*CN + (size_t)nt*64) * CD;
  float4 w4 = *(const float4*)(gw + 4*l);
  float4 b4 = *(const float4*)(gb + 4*l);
  for(int i = 0; i < 16; i++){
    int r = wv*16 + i;
    float4 v = *(const float4*)(base + (size_t)r*CD + 4*l);
    float s1 = v.x + v.y + v.z + v.w;
    float s2 = v.x*v.x + v.y*v.y + v.z*v.z + v.w*v.w;
    #pragma unroll
    for(int m = 1; m < 64; m <<= 1){ s1 += __shfl_xor(s1, m); s2 += __shfl_xor(s2, m); }
    float mean = s1 * (1.0f/CD);
    float var  = fmaxf(s2 * (1.0f/CD) - mean*mean, 0.0f);
    float rstd = rsqrtf(var + 1e-5f);
    float y0 = (v.x - mean)*rstd*w4.x + b4.x;
    float y1 = (v.y - mean)*rstd*w4.y + b4.y;
    float y2 = (v.z - mean)*rstd*w4.z + b4.z;
    float y3 = (v.w - mean)*rstd*w4.w + b4.w;
    uint2 p;
    p.x = (unsigned)f2bf(y0) | ((unsigned)f2bf(y1) << 16);
    p.y = (unsigned)f2bf(y2) | ((unsigned)f2bf(y3) << 16);
    *(uint2*)(xb + (size_t)r*CD + 4*l) = p;
  }
}

// ---------------- fused setup: M1T(bf16), bf16 weights [N][K], slots init ----------------
__global__ __launch_bounds__(256) void k_setup(
    const float* __restrict__ Wq, const float* __restrict__ Wk,
    const float* __restrict__ wih, const float* __restrict__ Wv,
    const float* __restrict__ whh, const float* __restrict__ w1,
    const float* __restrict__ w2, const float* __restrict__ noise,
    const float* __restrict__ mu, const float* __restrict__ lsig,
    unsigned short* __restrict__ M1T, unsigned short* __restrict__ Mih_bf,
    unsigned short* __restrict__ Whh_bf, unsigned short* __restrict__ w1_bf,
    unsigned short* __restrict__ w2_bf, float* __restrict__ slots){
  int bid = blockIdx.x, tid = threadIdx.x;
  if(bid < 256){                       // M1T[ep][e] = scale * sum_d Wq[d][e]*Wk[d][ep]
    int ep = bid, e = tid;
    float acc = 0.0f;
    for(int d = 0; d < 256; d++) acc = fmaf(Wq[(size_t)d*256 + e], Wk[(size_t)d*256 + ep], acc);
    M1T[(size_t)ep*256 + e] = f2bf(acc * 0.0625f);
  } else if(bid < 1024){               // Mih_bf[j][e] = sum_d wih[j][d]*Wv[d][e]  (768x256)
    int j = bid - 256, e = tid;
    float acc = 0.0f;
    for(int d = 0; d < 256; d++) acc = fmaf(wih[(size_t)j*256 + d], Wv[(size_t)d*256 + e], acc);
    Mih_bf[(size_t)j*256 + e] = f2bf(acc);
  } else if(bid < 1792){               // Whh_bf = bf16(whh), 768x256 row-major
    int idx = (bid - 1024)*256 + tid;
    Whh_bf[idx] = f2bf(whh[idx]);
  } else if(bid < 2304){               // w1_bf = bf16(w1), 512x256
    int idx = (bid - 1792)*256 + tid;
    w1_bf[idx] = f2bf(w1[idx]);
  } else if(bid < 2816){               // w2_bf = bf16(w2), 256x512
    int idx = (bid - 2304)*256 + tid;
    w2_bf[idx] = f2bf(w2[idx]);
  } else {                             // slots init, 131072 elems
    int idx = (bid - 2816)*256 + tid;
    int d = idx & 255;
    slots[idx] = mu[d] + __expf(lsig[d]) * noise[idx];
  }
}

// ---------------- qt = scale*LN(slots)@M1 (bf16, rows 8..15 zero); also zeros U,den ----------------
__global__ __launch_bounds__(256) void k_qt(const float* __restrict__ slots,
    const float* __restrict__ lw, const float* __restrict__ lb,
    const unsigned short* __restrict__ M1T, unsigned short* __restrict__ qt,
    float* __restrict__ U, float* __restrict__ den){
  __shared__ unsigned short sn[16*264];
  int b = blockIdx.x;
  int tid = threadIdx.x;
  float4 z4 = {0.f, 0.f, 0.f, 0.f};
  float* Ub = U + (size_t)b*CS*CD;
  *(float4*)(Ub + tid*8)     = z4;
  *(float4*)(Ub + tid*8 + 4) = z4;
  if(tid < CS) den[b*CS + tid] = 0.0f;

  int wv = tid >> 6, l = tid & 63;
  int lm = l & 15, lg = l >> 4;
  float4 w4 = *(const float4*)(lw + 4*l);
  float4 b4 = *(const float4*)(lb + 4*l);
  for(int i = 0; i < 2; i++){
    int r = wv*2 + i;
    float4 v = *(const float4*)(slots + ((size_t)b*CS + r)*CD + 4*l);
    float s1 = v.x + v.y + v.z + v.w;
    float s2 = v.x*v.x + v.y*v.y + v.z*v.z + v.w*v.w;
    #pragma unroll
    for(int m = 1; m < 64; m <<= 1){ s1 += __shfl_xor(s1, m); s2 += __shfl_xor(s2, m); }
    float mean = s1 * (1.0f/CD);
    float var  = fmaxf(s2 * (1.0f/CD) - mean*mean, 0.0f);
    float rstd = rsqrtf(var + 1e-5f);
    float y0 = (v.x - mean)*rstd*w4.x + b4.x;
    float y1 = (v.y - mean)*rstd*w4.y + b4.y;
    float y2 = (v.z - mean)*rstd*w4.z + b4.z;
    float y3 = (v.w - mean)*rstd*w4.w + b4.w;
    uint2 p;
    p.x = (unsigned)f2bf(y0) | ((unsigned)f2bf(y1) << 16);
    p.y = (unsigned)f2bf(y2) | ((unsigned)f2bf(y3) << 16);
    *(uint2*)(&sn[r*264 + 4*l]) = p;
    uint2 zz; zz.x = 0u; zz.y = 0u;
    *(uint2*)(&sn[(r+8)*264 + 4*l]) = zz;
  }
  __syncthreads();
  bf16x8 af[8];
  #pragma unroll
  for(int k = 0; k < 8; k++) af[k] = *(const bf16x8*)(&sn[lm*264 + k*32 + lg*8]);
  #pragma unroll
  for(int ntile = 0; ntile < 4; ntile++){
    int ep = wv*64 + ntile*16 + lm;
    f32x4 acc = {0.f, 0.f, 0.f, 0.f};
    const unsigned short* mrow = M1T + (size_t)ep*CD;
    #pragma unroll
    for(int k = 0; k < 8; k++){
      bf16x8 bf = *(const bf16x8*)(mrow + k*32 + lg*8);
      acc = mfma16(af[k], bf, acc);
    }
    #pragma unroll
    for(int reg = 0; reg < 4; reg++){
      int s = lg*4 + reg;
      qt[((size_t)b*16 + s)*CD + ep] = f2bf(acc[reg]);
    }
  }
}

// ---------------- fused attention pass: logits -> softmax+eps -> U,den ----------------
__global__ __launch_bounds__(256) void k_attn(const unsigned short* __restrict__ x,
    const unsigned short* __restrict__ qt, float* __restrict__ U, float* __restrict__ den){
  __shared__ unsigned short xt[64*256];
  __shared__ unsigned short pt[16*72];
  int b = blockIdx.x >> 4, chunk = blockIdx.x & 15;   // 16 chunks -> 1024 blocks
  int wv = threadIdx.x >> 6, l = threadIdx.x & 63;
  int lm = l & 15, lg = l >> 4;

  bf16x8 qb[8];
  const unsigned short* qrow = qt + ((size_t)b*16 + lm)*CD;
  #pragma unroll
  for(int k = 0; k < 8; k++) qb[k] = *(const bf16x8*)(qrow + k*32 + lg*8);

  f32x4 uacc[4];
  #pragma unroll
  for(int nt = 0; nt < 4; nt++){ f32x4 z = {0.f,0.f,0.f,0.f}; uacc[nt] = z; }
  float dacc = 0.0f;

  const unsigned short* xbatch = x + (size_t)b*CN*CD + (size_t)chunk*256*CD;

  for(int t = 0; t < 4; t++){
    const unsigned short* xtile = xbatch + (size_t)t*64*CD;
    __syncthreads();
    #pragma unroll
    for(int k2 = 0; k2 < 8; k2++){
      int r0 = wv*16 + k2*2;
      int row = r0 + (l >> 5);
      int c = l & 31;
      int f = (row ^ (row >> 3)) & 7;
      const unsigned short* g = xtile + (size_t)row*CD + (size_t)(c ^ f)*8;
      gl_lds16(g, &xt[r0*CD]);
    }
    __syncthreads();

    // phase 1: logits for this wave's 16 rows
    f32x4 c4 = {0.f, 0.f, 0.f, 0.f};
    int rowl = wv*16 + lm;
    int f1 = (rowl ^ (rowl >> 3)) & 7;
    #pragma unroll
    for(int k = 0; k < 8; k++){
      int cc = (k*4 + lg) ^ f1;
      bf16x8 a = *(const bf16x8*)(&xt[rowl*256 + cc*8]);
      c4 = mfma16(a, qb[k], c4);
    }
    // softmax over slots
    float pv[4];
    #pragma unroll
    for(int reg = 0; reg < 4; reg++){
      float v = (lm < 8) ? c4[reg] : -1e30f;
      float mx = v;
      #pragma unroll
      for(int m = 1; m < 16; m <<= 1) mx = fmaxf(mx, __shfl_xor(mx, m));
      float e = __expf(v - mx);
      float s = e;
      #pragma unroll
      for(int m = 1; m < 16; m <<= 1) s += __shfl_xor(s, m);
      float p = (lm < 8) ? (e/s + 1e-8f) : 0.0f;
      dacc += p;
      pv[reg] = p;
    }
    int rbase = wv*16 + lg*4;
    unsigned int p01 = (unsigned)f2bf(pv[0]) | ((unsigned)f2bf(pv[1]) << 16);
    unsigned int p23 = (unsigned)f2bf(pv[2]) | ((unsigned)f2bf(pv[3]) << 16);
    *(unsigned int*)(&pt[lm*72 + rbase])     = p01;
    *(unsigned int*)(&pt[lm*72 + rbase + 2]) = p23;
    __syncthreads();

    // phase 2: U[s, e-slice] += P^T @ X
    #pragma unroll
    for(int ks = 0; ks < 2; ks++){
      bf16x8 a = *(const bf16x8*)(&pt[lm*72 + ks*32 + lg*8]);
      int rb = ks*32 + lg*8;
      #pragma unroll
      for(int nt = 0; nt < 4; nt++){
        int e = wv*64 + nt*16 + lm;
        bf16x8 bfr;
        #pragma unroll
        for(int j = 0; j < 8; j++){
          int row2 = rb + j;
          int f2 = (row2 ^ (row2 >> 3)) & 7;
          int cidx = (e >> 3) ^ f2;
          unsigned short tv = xt[row2*256 + cidx*8 + (e & 7)];
          bfr[j] = __builtin_bit_cast(bf16_t, tv);
        }
        uacc[nt] = mfma16(a, bfr, uacc[nt]);
      }
    }
  }

  // epilogue
  dacc += __shfl_xor(dacc, 16);
  dacc += __shfl_xor(dacc, 32);
  if(l < 8) atomicAdd(&den[b*CS + l], dacc);
  if(lg < 2){
    #pragma unroll
    for(int nt = 0; nt < 4; nt++){
      #pragma unroll
      for(int reg = 0; reg < 4; reg++){
        int s = lg*4 + reg;
        atomicAdd(&U[((size_t)b*CS + s)*CD + wv*64 + nt*16 + lm], uacc[nt][reg]);
      }
    }
  }
}

// ---------------- fused slot update: gates GEMM + GRU act + LN + MLP + qt(next) + U/den zero ----
// One block per batch b (8 slot rows). All math row-local; weights stream from L2.
// Replaces k_gemm(gates) + k_act + k_gemm(h1) + k_gemm(out) + k_qt(next iter).
__global__ __launch_bounds__(256) void k_update(
    const float* __restrict__ U, const float* slots,
    const float* __restrict__ den,
    const unsigned short* __restrict__ Mih, const unsigned short* __restrict__ Whh,
    const unsigned short* __restrict__ w1b, const unsigned short* __restrict__ w2b,
    const unsigned short* __restrict__ M1T,
    const float* __restrict__ bih, const float* __restrict__ bhh,
    const float* __restrict__ lmw, const float* __restrict__ lmb,
    const float* __restrict__ b1, const float* __restrict__ b2,
    const float* __restrict__ lsw, const float* __restrict__ lsb,
    float* out, unsigned short* __restrict__ qt,
    float* __restrict__ Uz, float* __restrict__ denz, int last){
  __shared__ unsigned short A1[16*264];   // bf16 A-operand: U -> lnh -> ln(slots_new)
  __shared__ unsigned short SBf[16*264];  // bf16 slots (gh A-operand)
  __shared__ unsigned short A3[16*520];   // bf16 h1 (K=512)
  __shared__ float G1[8*777];             // gi raw (768 cols, odd stride)
  __shared__ float G2[8*777];             // gh raw
  __shared__ float Hh[8*257];             // GRU output h (residual base)
  __shared__ float SN[8*257];             // slots_new f32 (for qt LN)
  int b = blockIdx.x, tid = threadIdx.x;
  int l = tid & 63, lm = l & 15, lg = l >> 4;
  int wv = tid >> 6;

  // zero pad rows 8..15 (A-fragment rows; keeps D rows 8..15 = 0)
  for(int i = tid; i < 8*264; i += 256){ A1[8*264 + i] = 0; SBf[8*264 + i] = 0; }
  for(int i = tid; i < 8*520; i += 256) A3[8*520 + i] = 0;
  // stage U, slots as bf16 (8 rows x 256)
  {
    int r = tid >> 5, c = (tid & 31)*8;
    const float* Ur = U + ((size_t)b*CS + r)*CD + c;
    float4 a0 = *(const float4*)Ur, a1 = *(const float4*)(Ur + 4);
    uint4 pk;
    pk.x = (unsigned)f2bf(a0.x) | ((unsigned)f2bf(a0.y) << 16);
    pk.y = (unsigned)f2bf(a0.z) | ((unsigned)f2bf(a0.w) << 16);
    pk.z = (unsigned)f2bf(a1.x) | ((unsigned)f2bf(a1.y) << 16);
    pk.w = (unsigned)f2bf(a1.z) | ((unsigned)f2bf(a1.w) << 16);
    *(uint4*)(&A1[r*264 + c]) = pk;
    const float* Sr = slots + ((size_t)b*CS + r)*CD + c;
    a0 = *(const float4*)Sr; a1 = *(const float4*)(Sr + 4);
    pk.x = (unsigned)f2bf(a0.x) | ((unsigned)f2bf(a0.y) << 16);
    pk.y = (unsigned)f2bf(a0.z) | ((unsigned)f2bf(a0.w) << 16);
    pk.z = (unsigned)f2bf(a1.x) | ((unsigned)f2bf(a1.y) << 16);
    pk.w = (unsigned)f2bf(a1.z) | ((unsigned)f2bf(a1.w) << 16);
    *(uint4*)(&SBf[r*264 + c]) = pk;
  }
  __syncthreads();

  // P1: gi = U@Mih^T, gh = slots@Whh^T   (N=768 each, K=256; wave covers 192 cols)
  {
    bf16x8 afU[8], afS[8];
    #pragma unroll
    for(int k = 0; k < 8; k++){
      afU[k] = *(const bf16x8*)(&A1[lm*264 + k*32 + lg*8]);
      afS[k] = *(const bf16x8*)(&SBf[lm*264 + k*32 + lg*8]);
    }
    for(int t = 0; t < 12; t++){
      int nb = wv*192 + t*16;
      const unsigned short* br1 = Mih + (size_t)(nb + lm)*CD;
      const unsigned short* br2 = Whh + (size_t)(nb + lm)*CD;
      f32x4 ac1 = {0.f,0.f,0.f,0.f}, ac2 = {0.f,0.f,0.f,0.f};
      #pragma unroll
      for(int k = 0; k < 8; k++){
        bf16x8 bv1 = *(const bf16x8*)(br1 + k*32 + lg*8);
        ac1 = mfma16(afU[k], bv1, ac1);
        bf16x8 bv2 = *(const bf16x8*)(br2 + k*32 + lg*8);
        ac2 = mfma16(afS[k], bv2, ac2);
      }
      if(lg < 2){
        #pragma unroll
        for(int reg = 0; reg < 4; reg++){
          int row = lg*4 + reg;
          G1[row*777 + nb + lm] = ac1[reg];
          G2[row*777 + nb + lm] = ac2[reg];
        }
      }
    }
  }
  __syncthreads();

  // P2: GRU gate activations + LN(mlp) -> A1 (bf16 lnh)
  {
    int r = tid >> 5, cl = tid & 31;
    float invd = 1.0f / den[b*CS + r];
    const float* srow = slots + ((size_t)b*CS + r)*CD;
    float hv[8]; float s1 = 0.f, s2 = 0.f;
    #pragma unroll
    for(int i = 0; i < 8; i++){
      int c = cl + 32*i;
      float gr = G1[r*777 + c]*invd + bih[c] + G2[r*777 + c] + bhh[c];
      float gz = G1[r*777 + 256 + c]*invd + bih[256 + c] + G2[r*777 + 256 + c] + bhh[256 + c];
      float gn = G1[r*777 + 512 + c]*invd + bih[512 + c];
      float hn = G2[r*777 + 512 + c] + bhh[512 + c];
      float rr = 1.0f/(1.0f + __expf(-gr));
      float zz = 1.0f/(1.0f + __expf(-gz));
      float nn = tanhf(gn + rr*hn);
      float h = (1.0f - zz)*nn + zz*srow[c];
      hv[i] = h; Hh[r*257 + c] = h; s1 += h; s2 += h*h;
    }
    #pragma unroll
    for(int m = 1; m < 32; m <<= 1){ s1 += __shfl_xor(s1, m); s2 += __shfl_xor(s2, m); }
    float mean = s1 * (1.0f/CD);
    float var  = fmaxf(s2 * (1.0f/CD) - mean*mean, 0.0f);
    float rstd = rsqrtf(var + 1e-5f);
    #pragma unroll
    for(int i = 0; i < 8; i++){
      int c = cl + 32*i;
      A1[r*264 + c] = f2bf((hv[i] - mean)*rstd*lmw[c] + lmb[c]);
    }
  }
  __syncthreads();

  // P3: h1 = relu(lnh@w1^T + b1) -> A3 bf16   (N=512, K=256; wave covers 128 cols)
  {
    bf16x8 af[8];
    #pragma unroll
    for(int k = 0; k < 8; k++) af[k] = *(const bf16x8*)(&A1[lm*264 + k*32 + lg*8]);
    for(int t = 0; t < 8; t++){
      int nb = wv*128 + t*16;
      const unsigned short* br = w1b + (size_t)(nb + lm)*CD;
      f32x4 acc = {0.f,0.f,0.f,0.f};
      #pragma unroll
      for(int k = 0; k < 8; k++){
        bf16x8 bv = *(const bf16x8*)(br + k*32 + lg*8);
        acc = mfma16(af[k], bv, acc);
      }
      if(lg < 2){
        int c = nb + lm;
        float bb = b1[c];
        #pragma unroll
        for(int reg = 0; reg < 4; reg++)
          A3[(lg*4 + reg)*520 + c] = f2bf(fmaxf(acc[reg] + bb, 0.0f));
      }
    }
  }
  __syncthreads();

  // P4: out = h1@w2^T + b2 + Hh   (N=256, K=512; wave covers 64 cols)
  {
    bf16x8 af[16];
    #pragma unroll
    for(int k = 0; k < 16; k++) af[k] = *(const bf16x8*)(&A3[lm*520 + k*32 + lg*8]);
    for(int t = 0; t < 4; t++){
      int nb = wv*64 + t*16;
      const unsigned short* br = w2b + (size_t)(nb + lm)*CH;
      f32x4 acc = {0.f,0.f,0.f,0.f};
      #pragma unroll
      for(int k = 0; k < 16; k++){
        bf16x8 bv = *(const bf16x8*)(br + k*32 + lg*8);
        acc = mfma16(af[k], bv, acc);
      }
      if(lg < 2){
        int c = nb + lm;
        float bb = b2[c];
        #pragma unroll
        for(int reg = 0; reg < 4; reg++){
          int row = lg*4 + reg;
          float v = acc[reg] + bb + Hh[row*257 + c];
          out[((size_t)b*CS + row)*CD + c] = v;
          SN[row*257 + c] = v;
        }
      }
    }
  }
  if(last) return;
  __syncthreads();

  // P5: qt(next) = LN(slots_new)@M1  (rows 8..15 of qt stay zero from initial k_qt)
  {
    int r = tid >> 5, cl = tid & 31;
    float sv[8]; float s1 = 0.f, s2 = 0.f;
    #pragma unroll
    for(int i = 0; i < 8; i++){
      int c = cl + 32*i;
      float v = SN[r*257 + c]; sv[i] = v; s1 += v; s2 += v*v;
    }
    #pragma unroll
    for(int m = 1; m < 32; m <<= 1){ s1 += __shfl_xor(s1, m); s2 += __shfl_xor(s2, m); }
    float mean = s1 * (1.0f/CD);
    float var  = fmaxf(s2 * (1.0f/CD) - mean*mean, 0.0f);
    float rstd = rsqrtf(var + 1e-5f);
    #pragma unroll
    for(int i = 0; i < 8; i++){
      int c = cl + 32*i;
      A1[r*264 + c] = f2bf((sv[i] - mean)*rstd*lsw[c] + lsb[c]);
    }
  }
  __syncthreads();
  {
    bf16x8 af[8];
    #pragma unroll
    for(int k = 0; k < 8; k++) af[k] = *(const bf16x8*)(&A1[lm*264 + k*32 + lg*8]);
    for(int t = 0; t < 4; t++){
      int nb = wv*64 + t*16;
      const unsigned short* br = M1T + (size_t)(nb + lm)*CD;
      f32x4 acc = {0.f,0.f,0.f,0.f};
      #pragma unroll
      for(int k = 0; k < 8; k++){
        bf16x8 bv = *(const bf16x8*)(br + k*32 + lg*8);
        acc = mfma16(af[k], bv, acc);
      }
      if(lg < 2){
        int c = nb + lm;
        #pragma unroll
        for(int reg = 0; reg < 4; reg++)
          qt[((size_t)b*16 + lg*4 + reg)*CD + c] = f2bf(acc[reg]);
      }
    }
  }
  // P6: zero U, den for next k_attn
  {
    float4 z4 = {0.f,0.f,0.f,0.f};
    float* Ub = Uz + (size_t)b*CS*CD;
    *(float4*)(Ub + tid*8)     = z4;
    *(float4*)(Ub + tid*8 + 4) = z4;
    if(tid < CS) denz[b*CS + tid] = 0.0f;
  }
}

extern "C" void kernel_launch(void* const* d_in, const int* in_sizes, int n_in,
                              void* d_out, int out_size, void* d_ws, size_t ws_size,
                              hipStream_t stream){
  const float* inputs = (const float*)d_in[0];
  const float* noise  = (const float*)d_in[1];
  const float* ln_in_w = (const float*)d_in[2];
  const float* ln_in_b = (const float*)d_in[3];
  const float* ln_sl_w = (const float*)d_in[4];
  const float* ln_sl_b = (const float*)d_in[5];
  const float* ln_ml_w = (const float*)d_in[6];
  const float* ln_ml_b = (const float*)d_in[7];
  const float* mu   = (const float*)d_in[8];
  const float* lsig = (const float*)d_in[9];
  const float* Wq  = (const float*)d_in[10];
  const float* Wk  = (const float*)d_in[11];
  const float* Wv  = (const float*)d_in[12];
  const float* wih = (const float*)d_in[13];
  const float* whh = (const float*)d_in[14];
  const float* bih = (const float*)d_in[15];
  const float* bhh = (const float*)d_in[16];
  const float* w1  = (const float*)d_in[17];
  const float* b1  = (const float*)d_in[18];
  const float* w2  = (const float*)d_in[19];
  const float* b2  = (const float*)d_in[20];

  char* ws = (char*)d_ws;
  size_t off = 0;
  unsigned short* x = (unsigned short*)(ws + off); off += (size_t)CB*CN*CD*2;
  float* slots = (float*)(ws + off); off += (size_t)CB*CS*CD*4;
  float* U     = (float*)(ws + off); off += (size_t)CB*CS*CD*4;
  float* den   = (float*)(ws + off); off += (size_t)CB*CS*4;
  unsigned short* qt     = (unsigned short*)(ws + off); off += (size_t)CB*16*CD*2;
  unsigned short* M1T    = (unsigned short*)(ws + off); off += (size_t)CD*CD*2;
  unsigned short* Mih_bf = (unsigned short*)(ws + off); off += (size_t)768*CD*2;
  unsigned short* Whh_bf = (unsigned short*)(ws + off); off += (size_t)768*CD*2;
  unsigned short* w1_bf  = (unsigned short*)(ws + off); off += (size_t)CH*CD*2;
  unsigned short* w2_bf  = (unsigned short*)(ws + off); off += (size_t)CD*CH*2;

  k_ln<<<4096, 256, 0, stream>>>(inputs, ln_in_w, ln_in_b, x);
  k_setup<<<3328, 256, 0, stream>>>(Wq, Wk, wih, Wv, whh, w1, w2, noise, mu, lsig,
                                    M1T, Mih_bf, Whh_bf, w1_bf, w2_bf, slots);
  k_qt<<<64, 256, 0, stream>>>(slots, ln_sl_w, ln_sl_b, M1T, qt, U, den);

  for(int it = 0; it < 3; it++){
    k_attn<<<1024, 256, 0, stream>>>(x, qt, U, den);
    float* dst = (it == 2) ? (float*)d_out : slots;
    k_update<<<64, 256, 0, stream>>>(U, slots, den,
        Mih_bf, Whh_bf, w1_bf, w2_bf, M1T,
        bih, bhh, ln_ml_w, ln_ml_b, b1, b2, ln_sl_w, ln_sl_b,
        dst, qt, U, den, (it == 2) ? 1 : 0);
  }
}

// Round 3
// 684.379 us; speedup vs baseline: 1.0389x; 1.0389x over previous
//
#include <hip/hip_runtime.h>

#define CB 64
#define CN 4096
#define CD 256
#define CS 8
#define CH 512

typedef __bf16 bf16_t;
typedef bf16_t bf16x8 __attribute__((ext_vector_type(8)));
typedef float f32x4 __attribute__((ext_vector_type(4)));

__device__ __forceinline__ unsigned short f2bf(float f){
  unsigned int u = __builtin_bit_cast(unsigned int, f);
  u += 0x7FFFu + ((u >> 16) & 1u);
  return (unsigned short)(u >> 16);
}

__device__ __forceinline__ f32x4 mfma16(bf16x8 a, bf16x8 b, f32x4 c){
  return __builtin_amdgcn_mfma_f32_16x16x32_bf16(a, b, c, 0, 0, 0);
}

__device__ __forceinline__ void gl_lds16(const void* g, void* l){
  __builtin_amdgcn_global_load_lds(
      (const __attribute__((address_space(1))) unsigned int*)g,
      (__attribute__((address_space(3))) unsigned int*)l, 16, 0, 0);
}

// ---------------- LN over inputs -> x (bf16, row-major) ----------------
__global__ __launch_bounds__(256) void k_ln(const float* __restrict__ in,
    const float* __restrict__ gw, const float* __restrict__ gb,
    unsigned short* __restrict__ x){
  int blk = blockIdx.x;            // 4096 = 64 b * 64 ntiles
  int b = blk >> 6, nt = blk & 63;
  int wv = threadIdx.x >> 6, l = threadIdx.x & 63;
  const float* base = in + ((size_t)b*CN + (size_t)nt*64) * CD;
  unsigned short* xb = x + ((size_t)b*CN + (size_t)nt*64) * CD;
  float4 w4 = *(const float4*)(gw + 4*l);
  float4 b4 = *(const float4*)(gb + 4*l);
  for(int i = 0; i < 16; i++){
    int r = wv*16 + i;
    float4 v = *(const float4*)(base + (size_t)r*CD + 4*l);
    float s1 = v.x + v.y + v.z + v.w;
    float s2 = v.x*v.x + v.y*v.y + v.z*v.z + v.w*v.w;
    #pragma unroll
    for(int m = 1; m < 64; m <<= 1){ s1 += __shfl_xor(s1, m); s2 += __shfl_xor(s2, m); }
    float mean = s1 * (1.0f/CD);
    float var  = fmaxf(s2 * (1.0f/CD) - mean*mean, 0.0f);
    float rstd = rsqrtf(var + 1e-5f);
    float y0 = (v.x - mean)*rstd*w4.x + b4.x;
    float y1 = (v.y - mean)*rstd*w4.y + b4.y;
    float y2 = (v.z - mean)*rstd*w4.z + b4.z;
    float y3 = (v.w - mean)*rstd*w4.w + b4.w;
    uint2 p;
    p.x = (unsigned)f2bf(y0) | ((unsigned)f2bf(y1) << 16);
    p.y = (unsigned)f2bf(y2) | ((unsigned)f2bf(y3) << 16);
    *(uint2*)(xb + (size_t)r*CD + 4*l) = p;
  }
}

// ---------------- fused setup: M1T(bf16), bf16 weights [N][K], slots init ----------------
__global__ __launch_bounds__(256) void k_setup(
    const float* __restrict__ Wq, const float* __restrict__ Wk,
    const float* __restrict__ wih, const float* __restrict__ Wv,
    const float* __restrict__ whh, const float* __restrict__ w1,
    const float* __restrict__ w2, const float* __restrict__ noise,
    const float* __restrict__ mu, const float* __restrict__ lsig,
    unsigned short* __restrict__ M1T, unsigned short* __restrict__ Mih_bf,
    unsigned short* __restrict__ Whh_bf, unsigned short* __restrict__ w1_bf,
    unsigned short* __restrict__ w2_bf, float* __restrict__ slots){
  int bid = blockIdx.x, tid = threadIdx.x;
  if(bid < 256){                       // M1T[ep][e] = scale * sum_d Wq[d][e]*Wk[d][ep]
    int ep = bid, e = tid;
    float acc = 0.0f;
    for(int d = 0; d < 256; d++) acc = fmaf(Wq[(size_t)d*256 + e], Wk[(size_t)d*256 + ep], acc);
    M1T[(size_t)ep*256 + e] = f2bf(acc * 0.0625f);
  } else if(bid < 1024){               // Mih_bf[j][e] = sum_d wih[j][d]*Wv[d][e]  (768x256)
    int j = bid - 256, e = tid;
    float acc = 0.0f;
    for(int d = 0; d < 256; d++) acc = fmaf(wih[(size_t)j*256 + d], Wv[(size_t)d*256 + e], acc);
    Mih_bf[(size_t)j*256 + e] = f2bf(acc);
  } else if(bid < 1792){               // Whh_bf = bf16(whh), 768x256 row-major
    int idx = (bid - 1024)*256 + tid;
    Whh_bf[idx] = f2bf(whh[idx]);
  } else if(bid < 2304){               // w1_bf = bf16(w1), 512x256
    int idx = (bid - 1792)*256 + tid;
    w1_bf[idx] = f2bf(w1[idx]);
  } else if(bid < 2816){               // w2_bf = bf16(w2), 256x512
    int idx = (bid - 2304)*256 + tid;
    w2_bf[idx] = f2bf(w2[idx]);
  } else {                             // slots init, 131072 elems
    int idx = (bid - 2816)*256 + tid;
    int d = idx & 255;
    slots[idx] = mu[d] + __expf(lsig[d]) * noise[idx];
  }
}

// ---------------- qt = scale*LN(slots)@M1 (bf16, rows 8..15 zero); also zeros U,den ----------------
__global__ __launch_bounds__(256) void k_qt(const float* __restrict__ slots,
    const float* __restrict__ lw, const float* __restrict__ lb,
    const unsigned short* __restrict__ M1T, unsigned short* __restrict__ qt,
    float* __restrict__ U, float* __restrict__ den){
  __shared__ unsigned short sn[16*264];
  int b = blockIdx.x;
  int tid = threadIdx.x;
  float4 z4 = {0.f, 0.f, 0.f, 0.f};
  float* Ub = U + (size_t)b*CS*CD;
  *(float4*)(Ub + tid*8)     = z4;
  *(float4*)(Ub + tid*8 + 4) = z4;
  if(tid < CS) den[b*CS + tid] = 0.0f;

  int wv = tid >> 6, l = tid & 63;
  int lm = l & 15, lg = l >> 4;
  float4 w4 = *(const float4*)(lw + 4*l);
  float4 b4 = *(const float4*)(lb + 4*l);
  for(int i = 0; i < 2; i++){
    int r = wv*2 + i;
    float4 v = *(const float4*)(slots + ((size_t)b*CS + r)*CD + 4*l);
    float s1 = v.x + v.y + v.z + v.w;
    float s2 = v.x*v.x + v.y*v.y + v.z*v.z + v.w*v.w;
    #pragma unroll
    for(int m = 1; m < 64; m <<= 1){ s1 += __shfl_xor(s1, m); s2 += __shfl_xor(s2, m); }
    float mean = s1 * (1.0f/CD);
    float var  = fmaxf(s2 * (1.0f/CD) - mean*mean, 0.0f);
    float rstd = rsqrtf(var + 1e-5f);
    float y0 = (v.x - mean)*rstd*w4.x + b4.x;
    float y1 = (v.y - mean)*rstd*w4.y + b4.y;
    float y2 = (v.z - mean)*rstd*w4.z + b4.z;
    float y3 = (v.w - mean)*rstd*w4.w + b4.w;
    uint2 p;
    p.x = (unsigned)f2bf(y0) | ((unsigned)f2bf(y1) << 16);
    p.y = (unsigned)f2bf(y2) | ((unsigned)f2bf(y3) << 16);
    *(uint2*)(&sn[r*264 + 4*l]) = p;
    uint2 zz; zz.x = 0u; zz.y = 0u;
    *(uint2*)(&sn[(r+8)*264 + 4*l]) = zz;
  }
  __syncthreads();
  bf16x8 af[8];
  #pragma unroll
  for(int k = 0; k < 8; k++) af[k] = *(const bf16x8*)(&sn[lm*264 + k*32 + lg*8]);
  #pragma unroll
  for(int ntile = 0; ntile < 4; ntile++){
    int ep = wv*64 + ntile*16 + lm;
    f32x4 acc = {0.f, 0.f, 0.f, 0.f};
    const unsigned short* mrow = M1T + (size_t)ep*CD;
    #pragma unroll
    for(int k = 0; k < 8; k++){
      bf16x8 bf = *(const bf16x8*)(mrow + k*32 + lg*8);
      acc = mfma16(af[k], bf, acc);
    }
    #pragma unroll
    for(int reg = 0; reg < 4; reg++){
      int s = lg*4 + reg;
      qt[((size_t)b*16 + s)*CD + ep] = f2bf(acc[reg]);
    }
  }
}

// ---------------- fused attention pass: logits -> softmax+eps -> U,den ----------------
__global__ __launch_bounds__(256) void k_attn(const unsigned short* __restrict__ x,
    const unsigned short* __restrict__ qt, float* __restrict__ U, float* __restrict__ den){
  __shared__ unsigned short xt[64*256];
  __shared__ unsigned short pt[16*72];
  int b = blockIdx.x >> 4, chunk = blockIdx.x & 15;   // 16 chunks -> 1024 blocks
  int wv = threadIdx.x >> 6, l = threadIdx.x & 63;
  int lm = l & 15, lg = l >> 4;

  bf16x8 qb[8];
  const unsigned short* qrow = qt + ((size_t)b*16 + lm)*CD;
  #pragma unroll
  for(int k = 0; k < 8; k++) qb[k] = *(const bf16x8*)(qrow + k*32 + lg*8);

  f32x4 uacc[4];
  #pragma unroll
  for(int nt = 0; nt < 4; nt++){ f32x4 z = {0.f,0.f,0.f,0.f}; uacc[nt] = z; }
  float dacc = 0.0f;

  const unsigned short* xbatch = x + (size_t)b*CN*CD + (size_t)chunk*256*CD;

  for(int t = 0; t < 4; t++){
    const unsigned short* xtile = xbatch + (size_t)t*64*CD;
    __syncthreads();
    #pragma unroll
    for(int k2 = 0; k2 < 8; k2++){
      int r0 = wv*16 + k2*2;
      int row = r0 + (l >> 5);
      int c = l & 31;
      int f = (row ^ (row >> 3)) & 7;
      const unsigned short* g = xtile + (size_t)row*CD + (size_t)(c ^ f)*8;
      gl_lds16(g, &xt[r0*CD]);
    }
    __syncthreads();

    // phase 1: logits for this wave's 16 rows
    f32x4 c4 = {0.f, 0.f, 0.f, 0.f};
    int rowl = wv*16 + lm;
    int f1 = (rowl ^ (rowl >> 3)) & 7;
    #pragma unroll
    for(int k = 0; k < 8; k++){
      int cc = (k*4 + lg) ^ f1;
      bf16x8 a = *(const bf16x8*)(&xt[rowl*256 + cc*8]);
      c4 = mfma16(a, qb[k], c4);
    }
    // softmax over slots
    float pv[4];
    #pragma unroll
    for(int reg = 0; reg < 4; reg++){
      float v = (lm < 8) ? c4[reg] : -1e30f;
      float mx = v;
      #pragma unroll
      for(int m = 1; m < 16; m <<= 1) mx = fmaxf(mx, __shfl_xor(mx, m));
      float e = __expf(v - mx);
      float s = e;
      #pragma unroll
      for(int m = 1; m < 16; m <<= 1) s += __shfl_xor(s, m);
      float p = (lm < 8) ? (e/s + 1e-8f) : 0.0f;
      dacc += p;
      pv[reg] = p;
    }
    int rbase = wv*16 + lg*4;
    unsigned int p01 = (unsigned)f2bf(pv[0]) | ((unsigned)f2bf(pv[1]) << 16);
    unsigned int p23 = (unsigned)f2bf(pv[2]) | ((unsigned)f2bf(pv[3]) << 16);
    *(unsigned int*)(&pt[lm*72 + rbase])     = p01;
    *(unsigned int*)(&pt[lm*72 + rbase + 2]) = p23;
    __syncthreads();

    // phase 2: U[s, e-slice] += P^T @ X
    #pragma unroll
    for(int ks = 0; ks < 2; ks++){
      bf16x8 a = *(const bf16x8*)(&pt[lm*72 + ks*32 + lg*8]);
      int rb = ks*32 + lg*8;
      #pragma unroll
      for(int nt = 0; nt < 4; nt++){
        int e = wv*64 + nt*16 + lm;
        bf16x8 bfr;
        #pragma unroll
        for(int j = 0; j < 8; j++){
          int row2 = rb + j;
          int f2 = (row2 ^ (row2 >> 3)) & 7;
          int cidx = (e >> 3) ^ f2;
          unsigned short tv = xt[row2*256 + cidx*8 + (e & 7)];
          bfr[j] = __builtin_bit_cast(bf16_t, tv);
        }
        uacc[nt] = mfma16(a, bfr, uacc[nt]);
      }
    }
  }

  // epilogue
  dacc += __shfl_xor(dacc, 16);
  dacc += __shfl_xor(dacc, 32);
  if(l < 8) atomicAdd(&den[b*CS + l], dacc);
  if(lg < 2){
    #pragma unroll
    for(int nt = 0; nt < 4; nt++){
      #pragma unroll
      for(int reg = 0; reg < 4; reg++){
        int s = lg*4 + reg;
        atomicAdd(&U[((size_t)b*CS + s)*CD + wv*64 + nt*16 + lm], uacc[nt][reg]);
      }
    }
  }
}

// ---------------- fused slot update, 8-wave version (retry of round-2 submission) ----------------
// One block per batch b (8 slot rows), 512 threads = 8 waves (2 waves/SIMD).
// P1: gi (waves 0-3) and gh (waves 4-7) concurrently, double-buffered B stream.
// P2: GRU gates + LN(mlp), one wave per row. P3: h1. P4: out = h1@w2^T + b2 + h.
// Replaces gemm(gates) + k_act + gemm(h1) + gemm(out). qt & U/den zeroing stay in k_qt.
__global__ __launch_bounds__(512) void k_update(
    const float* __restrict__ U, const float* slots,
    const float* __restrict__ den,
    const unsigned short* __restrict__ Mih, const unsigned short* __restrict__ Whh,
    const unsigned short* __restrict__ w1b, const unsigned short* __restrict__ w2b,
    const float* __restrict__ bih, const float* __restrict__ bhh,
    const float* __restrict__ lmw, const float* __restrict__ lmb,
    const float* __restrict__ b1, const float* __restrict__ b2,
    float* out){
  __shared__ unsigned short A1[16*264];   // bf16 A-operand: U, then lnh
  __shared__ unsigned short SBf[16*264];  // bf16 slots
  __shared__ unsigned short A3[16*520];   // bf16 h1 (K=512)
  __shared__ float G1[8*777];             // gi raw
  __shared__ float G2[8*777];             // gh raw
  __shared__ float Hh[8*257];             // GRU output h (residual base)
  int b = blockIdx.x, tid = threadIdx.x;
  int l = tid & 63, lm = l & 15, lg = l >> 4;
  int wv = tid >> 6;

  // zero pad rows 8..15 of A-operands (keeps D rows 8..15 = 0)
  for(int i = tid; i < 8*264; i += 512){ A1[8*264 + i] = 0; SBf[8*264 + i] = 0; }
  for(int i = tid; i < 8*520; i += 512) A3[8*520 + i] = 0;
  // stage U (threads 0..255) and slots (threads 256..511) as bf16, 8 rows x 256
  {
    int t2 = tid & 255;
    int r = t2 >> 5, c = (t2 & 31)*8;
    const float* src = ((tid < 256) ? U : slots) + ((size_t)b*CS + r)*CD + c;
    float4 a0 = *(const float4*)src, a1 = *(const float4*)(src + 4);
    uint4 pk;
    pk.x = (unsigned)f2bf(a0.x) | ((unsigned)f2bf(a0.y) << 16);
    pk.y = (unsigned)f2bf(a0.z) | ((unsigned)f2bf(a0.w) << 16);
    pk.z = (unsigned)f2bf(a1.x) | ((unsigned)f2bf(a1.y) << 16);
    pk.w = (unsigned)f2bf(a1.z) | ((unsigned)f2bf(a1.w) << 16);
    if(tid < 256) *(uint4*)(&A1[r*264 + c]) = pk;
    else          *(uint4*)(&SBf[r*264 + c]) = pk;
  }
  __syncthreads();

  // P1: gi = U@Mih^T (waves 0-3), gh = slots@Whh^T (waves 4-7); N=768, K=256 each.
  // 12 col-tiles per wave, double-buffered B fragments streamed from L2.
  {
    const unsigned short* W = (wv < 4) ? Mih : Whh;
    const unsigned short* As = (wv < 4) ? A1 : SBf;
    float* G = (wv < 4) ? G1 : G2;
    int w4 = wv & 3;
    bf16x8 af[8];
    #pragma unroll
    for(int k = 0; k < 8; k++) af[k] = *(const bf16x8*)(&As[lm*264 + k*32 + lg*8]);
    const unsigned short* brow = W + ((size_t)(w4*192 + lm))*CD + lg*8;
    bf16x8 bv[8], bw[8];
    #pragma unroll
    for(int k = 0; k < 8; k++) bv[k] = *(const bf16x8*)(brow + k*32);
    for(int t = 0; t < 12; t++){
      if(t < 11){
        const unsigned short* bn = brow + (size_t)(t + 1)*16*CD;
        #pragma unroll
        for(int k = 0; k < 8; k++) bw[k] = *(const bf16x8*)(bn + k*32);
      }
      f32x4 acc = {0.f,0.f,0.f,0.f};
      #pragma unroll
      for(int k = 0; k < 8; k++) acc = mfma16(af[k], bv[k], acc);
      if(lg < 2){
        int cb = w4*192 + t*16 + lm;
        #pragma unroll
        for(int reg = 0; reg < 4; reg++) G[(lg*4 + reg)*777 + cb] = acc[reg];
      }
      #pragma unroll
      for(int k = 0; k < 8; k++) bv[k] = bw[k];
    }
  }
  __syncthreads();

  // P2: GRU gate activations + LN(mlp) -> A1 (bf16 lnh); one wave per slot row
  {
    int r = wv;
    float invd = 1.0f / den[b*CS + r];
    const float* srow = slots + ((size_t)b*CS + r)*CD;
    float hv[4]; float s1 = 0.f, s2 = 0.f;
    #pragma unroll
    for(int i = 0; i < 4; i++){
      int c = l + 64*i;
      float gr = G1[r*777 + c]*invd + bih[c] + G2[r*777 + c] + bhh[c];
      float gz = G1[r*777 + 256 + c]*invd + bih[256 + c] + G2[r*777 + 256 + c] + bhh[256 + c];
      float gn = G1[r*777 + 512 + c]*invd + bih[512 + c];
      float hn = G2[r*777 + 512 + c] + bhh[512 + c];
      float rr = 1.0f/(1.0f + __expf(-gr));
      float zz = 1.0f/(1.0f + __expf(-gz));
      float nn = tanhf(gn + rr*hn);
      float h = (1.0f - zz)*nn + zz*srow[c];
      hv[i] = h; Hh[r*257 + c] = h; s1 += h; s2 += h*h;
    }
    #pragma unroll
    for(int m = 1; m < 64; m <<= 1){ s1 += __shfl_xor(s1, m); s2 += __shfl_xor(s2, m); }
    float mean = s1 * (1.0f/CD);
    float var  = fmaxf(s2 * (1.0f/CD) - mean*mean, 0.0f);
    float rstd = rsqrtf(var + 1e-5f);
    #pragma unroll
    for(int i = 0; i < 4; i++){
      int c = l + 64*i;
      A1[r*264 + c] = f2bf((hv[i] - mean)*rstd*lmw[c] + lmb[c]);
    }
  }
  __syncthreads();

  // P3: h1 = relu(lnh@w1^T + b1) -> A3 bf16   (N=512, K=256; 4 col-tiles per wave)
  {
    bf16x8 af[8];
    #pragma unroll
    for(int k = 0; k < 8; k++) af[k] = *(const bf16x8*)(&A1[lm*264 + k*32 + lg*8]);
    const unsigned short* brow = w1b + ((size_t)(wv*64 + lm))*CD + lg*8;
    for(int t = 0; t < 4; t++){
      const unsigned short* bn = brow + (size_t)t*16*CD;
      f32x4 acc = {0.f,0.f,0.f,0.f};
      #pragma unroll
      for(int k = 0; k < 8; k++){
        bf16x8 bv = *(const bf16x8*)(bn + k*32);
        acc = mfma16(af[k], bv, acc);
      }
      if(lg < 2){
        int c = wv*64 + t*16 + lm;
        float bb = b1[c];
        #pragma unroll
        for(int reg = 0; reg < 4; reg++)
          A3[(lg*4 + reg)*520 + c] = f2bf(fmaxf(acc[reg] + bb, 0.0f));
      }
    }
  }
  __syncthreads();

  // P4: out = h1@w2^T + b2 + Hh   (N=256, K=512; 2 col-tiles per wave)
  {
    bf16x8 af[16];
    #pragma unroll
    for(int k = 0; k < 16; k++) af[k] = *(const bf16x8*)(&A3[lm*520 + k*32 + lg*8]);
    const unsigned short* brow = w2b + ((size_t)(wv*32 + lm))*CH + lg*8;
    for(int t = 0; t < 2; t++){
      const unsigned short* bn = brow + (size_t)t*16*CH;
      f32x4 acc = {0.f,0.f,0.f,0.f};
      #pragma unroll
      for(int k = 0; k < 16; k++){
        bf16x8 bv = *(const bf16x8*)(bn + k*32);
        acc = mfma16(af[k], bv, acc);
      }
      if(lg < 2){
        int c = wv*32 + t*16 + lm;
        float bb = b2[c];
        #pragma unroll
        for(int reg = 0; reg < 4; reg++){
          int row = lg*4 + reg;
          out[((size_t)b*CS + row)*CD + c] = acc[reg] + bb + Hh[row*257 + c];
        }
      }
    }
  }
}

extern "C" void kernel_launch(void* const* d_in, const int* in_sizes, int n_in,
                              void* d_out, int out_size, void* d_ws, size_t ws_size,
                              hipStream_t stream){
  const float* inputs = (const float*)d_in[0];
  const float* noise  = (const float*)d_in[1];
  const float* ln_in_w = (const float*)d_in[2];
  const float* ln_in_b = (const float*)d_in[3];
  const float* ln_sl_w = (const float*)d_in[4];
  const float* ln_sl_b = (const float*)d_in[5];
  const float* ln_ml_w = (const float*)d_in[6];
  const float* ln_ml_b = (const float*)d_in[7];
  const float* mu   = (const float*)d_in[8];
  const float* lsig = (const float*)d_in[9];
  const float* Wq  = (const float*)d_in[10];
  const float* Wk  = (const float*)d_in[11];
  const float* Wv  = (const float*)d_in[12];
  const float* wih = (const float*)d_in[13];
  const float* whh = (const float*)d_in[14];
  const float* bih = (const float*)d_in[15];
  const float* bhh = (const float*)d_in[16];
  const float* w1  = (const float*)d_in[17];
  const float* b1  = (const float*)d_in[18];
  const float* w2  = (const float*)d_in[19];
  const float* b2  = (const float*)d_in[20];

  char* ws = (char*)d_ws;
  size_t off = 0;
  unsigned short* x = (unsigned short*)(ws + off); off += (size_t)CB*CN*CD*2;
  float* slots = (float*)(ws + off); off += (size_t)CB*CS*CD*4;
  float* U     = (float*)(ws + off); off += (size_t)CB*CS*CD*4;
  float* den   = (float*)(ws + off); off += (size_t)CB*CS*4;
  unsigned short* qt     = (unsigned short*)(ws + off); off += (size_t)CB*16*CD*2;
  unsigned short* M1T    = (unsigned short*)(ws + off); off += (size_t)CD*CD*2;
  unsigned short* Mih_bf = (unsigned short*)(ws + off); off += (size_t)768*CD*2;
  unsigned short* Whh_bf = (unsigned short*)(ws + off); off += (size_t)768*CD*2;
  unsigned short* w1_bf  = (unsigned short*)(ws + off); off += (size_t)CH*CD*2;
  unsigned short* w2_bf  = (unsigned short*)(ws + off); off += (size_t)CD*CH*2;

  k_ln<<<4096, 256, 0, stream>>>(inputs, ln_in_w, ln_in_b, x);
  k_setup<<<3328, 256, 0, stream>>>(Wq, Wk, wih, Wv, whh, w1, w2, noise, mu, lsig,
                                    M1T, Mih_bf, Whh_bf, w1_bf, w2_bf, slots);

  for(int it = 0; it < 3; it++){
    k_qt<<<64, 256, 0, stream>>>(slots, ln_sl_w, ln_sl_b, M1T, qt, U, den);
    k_attn<<<1024, 256, 0, stream>>>(x, qt, U, den);
    float* dst = (it == 2) ? (float*)d_out : slots;
    k_update<<<64, 512, 0, stream>>>(U, slots, den,
        Mih_bf, Whh_bf, w1_bf, w2_bf,
        bih, bhh, ln_ml_w, ln_ml_b, b1, b2, dst);
  }
}

// Round 4
// 680.116 us; speedup vs baseline: 1.0454x; 1.0063x over previous
//
#include <hip/hip_runtime.h>

#define CB 64
#define CN 4096
#define CD 256
#define CS 8
#define CH 512

typedef __bf16 bf16_t;
typedef bf16_t bf16x8 __attribute__((ext_vector_type(8)));
typedef float f32x4 __attribute__((ext_vector_type(4)));

__device__ __forceinline__ unsigned short f2bf(float f){
  unsigned int u = __builtin_bit_cast(unsigned int, f);
  u += 0x7FFFu + ((u >> 16) & 1u);
  return (unsigned short)(u >> 16);
}

__device__ __forceinline__ f32x4 mfma16(bf16x8 a, bf16x8 b, f32x4 c){
  return __builtin_amdgcn_mfma_f32_16x16x32_bf16(a, b, c, 0, 0, 0);
}

__device__ __forceinline__ void gl_lds16(const void* g, void* l){
  __builtin_amdgcn_global_load_lds(
      (const __attribute__((address_space(1))) unsigned int*)g,
      (__attribute__((address_space(3))) unsigned int*)l, 16, 0, 0);
}

// ---------------- LN over inputs -> x (bf16, row-major) ----------------
__global__ __launch_bounds__(256) void k_ln(const float* __restrict__ in,
    const float* __restrict__ gw, const float* __restrict__ gb,
    unsigned short* __restrict__ x){
  int blk = blockIdx.x;            // 4096 = 64 b * 64 ntiles
  int b = blk >> 6, nt = blk & 63;
  int wv = threadIdx.x >> 6, l = threadIdx.x & 63;
  const float* base = in + ((size_t)b*CN + (size_t)nt*64) * CD;
  unsigned short* xb = x + ((size_t)b*CN + (size_t)nt*64) * CD;
  float4 w4 = *(const float4*)(gw + 4*l);
  float4 b4 = *(const float4*)(gb + 4*l);
  for(int i = 0; i < 16; i++){
    int r = wv*16 + i;
    float4 v = *(const float4*)(base + (size_t)r*CD + 4*l);
    float s1 = v.x + v.y + v.z + v.w;
    float s2 = v.x*v.x + v.y*v.y + v.z*v.z + v.w*v.w;
    #pragma unroll
    for(int m = 1; m < 64; m <<= 1){ s1 += __shfl_xor(s1, m); s2 += __shfl_xor(s2, m); }
    float mean = s1 * (1.0f/CD);
    float var  = fmaxf(s2 * (1.0f/CD) - mean*mean, 0.0f);
    float rstd = rsqrtf(var + 1e-5f);
    float y0 = (v.x - mean)*rstd*w4.x + b4.x;
    float y1 = (v.y - mean)*rstd*w4.y + b4.y;
    float y2 = (v.z - mean)*rstd*w4.z + b4.z;
    float y3 = (v.w - mean)*rstd*w4.w + b4.w;
    uint2 p;
    p.x = (unsigned)f2bf(y0) | ((unsigned)f2bf(y1) << 16);
    p.y = (unsigned)f2bf(y2) | ((unsigned)f2bf(y3) << 16);
    *(uint2*)(xb + (size_t)r*CD + 4*l) = p;
  }
}

// ---------------- fused setup: M1T(bf16), bf16 weights [N][K], slots init ----------------
__global__ __launch_bounds__(256) void k_setup(
    const float* __restrict__ Wq, const float* __restrict__ Wk,
    const float* __restrict__ wih, const float* __restrict__ Wv,
    const float* __restrict__ whh, const float* __restrict__ w1,
    const float* __restrict__ w2, const float* __restrict__ noise,
    const float* __restrict__ mu, const float* __restrict__ lsig,
    unsigned short* __restrict__ M1T, unsigned short* __restrict__ Mih_bf,
    unsigned short* __restrict__ Whh_bf, unsigned short* __restrict__ w1_bf,
    unsigned short* __restrict__ w2_bf, float* __restrict__ slots){
  int bid = blockIdx.x, tid = threadIdx.x;
  if(bid < 256){                       // M1T[ep][e] = scale * sum_d Wq[d][e]*Wk[d][ep]
    int ep = bid, e = tid;
    float acc = 0.0f;
    for(int d = 0; d < 256; d++) acc = fmaf(Wq[(size_t)d*256 + e], Wk[(size_t)d*256 + ep], acc);
    M1T[(size_t)ep*256 + e] = f2bf(acc * 0.0625f);
  } else if(bid < 1024){               // Mih_bf[j][e] = sum_d wih[j][d]*Wv[d][e]  (768x256)
    int j = bid - 256, e = tid;
    float acc = 0.0f;
    for(int d = 0; d < 256; d++) acc = fmaf(wih[(size_t)j*256 + d], Wv[(size_t)d*256 + e], acc);
    Mih_bf[(size_t)j*256 + e] = f2bf(acc);
  } else if(bid < 1792){               // Whh_bf = bf16(whh), 768x256 row-major
    int idx = (bid - 1024)*256 + tid;
    Whh_bf[idx] = f2bf(whh[idx]);
  } else if(bid < 2304){               // w1_bf = bf16(w1), 512x256
    int idx = (bid - 1792)*256 + tid;
    w1_bf[idx] = f2bf(w1[idx]);
  } else if(bid < 2816){               // w2_bf = bf16(w2), 256x512
    int idx = (bid - 2304)*256 + tid;
    w2_bf[idx] = f2bf(w2[idx]);
  } else {                             // slots init, 131072 elems
    int idx = (bid - 2816)*256 + tid;
    int d = idx & 255;
    slots[idx] = mu[d] + __expf(lsig[d]) * noise[idx];
  }
}

// ---------------- fused attention pass: qt prologue -> logits -> softmax+eps -> Upart,dpart ----
// qt computed per-block in LDS (reusing xt before staging). Partial outputs per chunk:
// Upart[chunk][b][s][e], dpart[chunk][b][s] — plain stores, no atomics.
__global__ __launch_bounds__(256) void k_attn(const unsigned short* __restrict__ x,
    const float* __restrict__ slots, const float* __restrict__ lsw,
    const float* __restrict__ lsb, const unsigned short* __restrict__ M1T,
    float* __restrict__ Upart, float* __restrict__ dpart){
  __shared__ unsigned short xt[64*256];
  __shared__ unsigned short pt[16*72];
  __shared__ float dred[4][8];
  int b = blockIdx.x >> 4, chunk = blockIdx.x & 15;   // 16 chunks -> 1024 blocks
  int tid = threadIdx.x;
  int wv = tid >> 6, l = tid & 63;
  int lm = l & 15, lg = l >> 4;

  // ---- prologue: qt[16][264] = scale*LN(slots)@M1 in LDS (rows 8..15 zero) ----
  unsigned short* sn    = xt;          // [16][264] bf16
  unsigned short* qtile = xt + 4224;   // [16][264] bf16
  {
    float4 w4 = *(const float4*)(lsw + 4*l);
    float4 b4 = *(const float4*)(lsb + 4*l);
    for(int i = 0; i < 2; i++){
      int r = wv*2 + i;
      float4 v = *(const float4*)(slots + ((size_t)b*CS + r)*CD + 4*l);
      float s1 = v.x + v.y + v.z + v.w;
      float s2 = v.x*v.x + v.y*v.y + v.z*v.z + v.w*v.w;
      #pragma unroll
      for(int m = 1; m < 64; m <<= 1){ s1 += __shfl_xor(s1, m); s2 += __shfl_xor(s2, m); }
      float mean = s1 * (1.0f/CD);
      float var  = fmaxf(s2 * (1.0f/CD) - mean*mean, 0.0f);
      float rstd = rsqrtf(var + 1e-5f);
      float y0 = (v.x - mean)*rstd*w4.x + b4.x;
      float y1 = (v.y - mean)*rstd*w4.y + b4.y;
      float y2 = (v.z - mean)*rstd*w4.z + b4.z;
      float y3 = (v.w - mean)*rstd*w4.w + b4.w;
      uint2 p;
      p.x = (unsigned)f2bf(y0) | ((unsigned)f2bf(y1) << 16);
      p.y = (unsigned)f2bf(y2) | ((unsigned)f2bf(y3) << 16);
      *(uint2*)(&sn[r*264 + 4*l]) = p;
      uint2 zz; zz.x = 0u; zz.y = 0u;
      *(uint2*)(&sn[(r+8)*264 + 4*l]) = zz;
    }
    __syncthreads();
    bf16x8 af[8];
    #pragma unroll
    for(int k = 0; k < 8; k++) af[k] = *(const bf16x8*)(&sn[lm*264 + k*32 + lg*8]);
    #pragma unroll
    for(int ntile = 0; ntile < 4; ntile++){
      int ep = wv*64 + ntile*16 + lm;
      f32x4 acc = {0.f, 0.f, 0.f, 0.f};
      const unsigned short* mrow = M1T + (size_t)ep*CD;
      #pragma unroll
      for(int k = 0; k < 8; k++){
        bf16x8 bf = *(const bf16x8*)(mrow + k*32 + lg*8);
        acc = mfma16(af[k], bf, acc);
      }
      #pragma unroll
      for(int reg = 0; reg < 4; reg++)
        qtile[(lg*4 + reg)*264 + ep] = f2bf(acc[reg]);
    }
    __syncthreads();
  }
  bf16x8 qb[8];
  #pragma unroll
  for(int k = 0; k < 8; k++) qb[k] = *(const bf16x8*)(&qtile[lm*264 + k*32 + lg*8]);

  f32x4 uacc[4];
  #pragma unroll
  for(int nt = 0; nt < 4; nt++){ f32x4 z = {0.f,0.f,0.f,0.f}; uacc[nt] = z; }
  float dacc = 0.0f;

  const unsigned short* xbatch = x + (size_t)b*CN*CD + (size_t)chunk*256*CD;

  for(int t = 0; t < 4; t++){
    const unsigned short* xtile = xbatch + (size_t)t*64*CD;
    __syncthreads();   // also drains qb/prologue LDS reads before DMA overwrites xt
    #pragma unroll
    for(int k2 = 0; k2 < 8; k2++){
      int r0 = wv*16 + k2*2;
      int row = r0 + (l >> 5);
      int c = l & 31;
      int f = (row ^ (row >> 3)) & 7;
      const unsigned short* g = xtile + (size_t)row*CD + (size_t)(c ^ f)*8;
      gl_lds16(g, &xt[r0*CD]);
    }
    __syncthreads();

    // phase 1: logits for this wave's 16 rows
    f32x4 c4 = {0.f, 0.f, 0.f, 0.f};
    int rowl = wv*16 + lm;
    int f1 = (rowl ^ (rowl >> 3)) & 7;
    #pragma unroll
    for(int k = 0; k < 8; k++){
      int cc = (k*4 + lg) ^ f1;
      bf16x8 a = *(const bf16x8*)(&xt[rowl*256 + cc*8]);
      c4 = mfma16(a, qb[k], c4);
    }
    // softmax over slots
    float pv[4];
    #pragma unroll
    for(int reg = 0; reg < 4; reg++){
      float v = (lm < 8) ? c4[reg] : -1e30f;
      float mx = v;
      #pragma unroll
      for(int m = 1; m < 16; m <<= 1) mx = fmaxf(mx, __shfl_xor(mx, m));
      float e = __expf(v - mx);
      float s = e;
      #pragma unroll
      for(int m = 1; m < 16; m <<= 1) s += __shfl_xor(s, m);
      float p = (lm < 8) ? (e/s + 1e-8f) : 0.0f;
      dacc += p;
      pv[reg] = p;
    }
    int rbase = wv*16 + lg*4;
    unsigned int p01 = (unsigned)f2bf(pv[0]) | ((unsigned)f2bf(pv[1]) << 16);
    unsigned int p23 = (unsigned)f2bf(pv[2]) | ((unsigned)f2bf(pv[3]) << 16);
    *(unsigned int*)(&pt[lm*72 + rbase])     = p01;
    *(unsigned int*)(&pt[lm*72 + rbase + 2]) = p23;
    __syncthreads();

    // phase 2: U[s, e-slice] += P^T @ X
    #pragma unroll
    for(int ks = 0; ks < 2; ks++){
      bf16x8 a = *(const bf16x8*)(&pt[lm*72 + ks*32 + lg*8]);
      int rb = ks*32 + lg*8;
      #pragma unroll
      for(int nt = 0; nt < 4; nt++){
        int e = wv*64 + nt*16 + lm;
        bf16x8 bfr;
        #pragma unroll
        for(int j = 0; j < 8; j++){
          int row2 = rb + j;
          int f2 = (row2 ^ (row2 >> 3)) & 7;
          int cidx = (e >> 3) ^ f2;
          unsigned short tv = xt[row2*256 + cidx*8 + (e & 7)];
          bfr[j] = __builtin_bit_cast(bf16_t, tv);
        }
        uacc[nt] = mfma16(a, bfr, uacc[nt]);
      }
    }
  }

  // epilogue: plain stores of partials (no atomics)
  dacc += __shfl_xor(dacc, 16);
  dacc += __shfl_xor(dacc, 32);
  if(l < 8) dred[wv][l] = dacc;
  if(lg < 2){
    float* Ub = Upart + (((size_t)chunk*CB + b)*CS)*CD;
    #pragma unroll
    for(int nt = 0; nt < 4; nt++){
      #pragma unroll
      for(int reg = 0; reg < 4; reg++){
        int s = lg*4 + reg;
        Ub[(size_t)s*CD + wv*64 + nt*16 + lm] = uacc[nt][reg];
      }
    }
  }
  __syncthreads();
  if(tid < 8)
    dpart[((size_t)chunk*CB + b)*CS + tid] =
        dred[0][tid] + dred[1][tid] + dred[2][tid] + dred[3][tid];
}

// ---------------- fused slot update, 8-wave; reduces 16 U/den partials in staging ----------------
__global__ __launch_bounds__(512) void k_update(
    const float* __restrict__ Upart, const float* slots,
    const float* __restrict__ dpart,
    const unsigned short* __restrict__ Mih, const unsigned short* __restrict__ Whh,
    const unsigned short* __restrict__ w1b, const unsigned short* __restrict__ w2b,
    const float* __restrict__ bih, const float* __restrict__ bhh,
    const float* __restrict__ lmw, const float* __restrict__ lmb,
    const float* __restrict__ b1, const float* __restrict__ b2,
    float* out){
  __shared__ unsigned short A1[16*264];   // bf16 A-operand: U, then lnh
  __shared__ unsigned short SBf[16*264];  // bf16 slots
  __shared__ unsigned short A3[16*520];   // bf16 h1 (K=512)
  __shared__ float G1[8*777];             // gi raw
  __shared__ float G2[8*777];             // gh raw
  __shared__ float Hh[8*257];             // GRU output h (residual base)
  int b = blockIdx.x, tid = threadIdx.x;
  int l = tid & 63, lm = l & 15, lg = l >> 4;
  int wv = tid >> 6;

  // zero pad rows 8..15 of A-operands (keeps D rows 8..15 = 0)
  for(int i = tid; i < 8*264; i += 512){ A1[8*264 + i] = 0; SBf[8*264 + i] = 0; }
  for(int i = tid; i < 8*520; i += 512) A3[8*520 + i] = 0;
  // stage U (threads 0..255, summing 16 partials) and slots (threads 256..511)
  if(tid < 256){
    int r = tid >> 5, c = (tid & 31)*8;
    float s0=0.f,s1=0.f,s2=0.f,s3=0.f,s4=0.f,s5=0.f,s6=0.f,s7=0.f;
    #pragma unroll
    for(int ch = 0; ch < 16; ch++){
      const float* Up = Upart + (((size_t)ch*CB + b)*CS + r)*CD + c;
      float4 a0 = *(const float4*)Up;
      float4 a1 = *(const float4*)(Up + 4);
      s0 += a0.x; s1 += a0.y; s2 += a0.z; s3 += a0.w;
      s4 += a1.x; s5 += a1.y; s6 += a1.z; s7 += a1.w;
    }
    uint4 pk;
    pk.x = (unsigned)f2bf(s0) | ((unsigned)f2bf(s1) << 16);
    pk.y = (unsigned)f2bf(s2) | ((unsigned)f2bf(s3) << 16);
    pk.z = (unsigned)f2bf(s4) | ((unsigned)f2bf(s5) << 16);
    pk.w = (unsigned)f2bf(s6) | ((unsigned)f2bf(s7) << 16);
    *(uint4*)(&A1[r*264 + c]) = pk;
  } else {
    int t2 = tid & 255;
    int r = t2 >> 5, c = (t2 & 31)*8;
    const float* src = slots + ((size_t)b*CS + r)*CD + c;
    float4 a0 = *(const float4*)src, a1 = *(const float4*)(src + 4);
    uint4 pk;
    pk.x = (unsigned)f2bf(a0.x) | ((unsigned)f2bf(a0.y) << 16);
    pk.y = (unsigned)f2bf(a0.z) | ((unsigned)f2bf(a0.w) << 16);
    pk.z = (unsigned)f2bf(a1.x) | ((unsigned)f2bf(a1.y) << 16);
    pk.w = (unsigned)f2bf(a1.z) | ((unsigned)f2bf(a1.w) << 16);
    *(uint4*)(&SBf[r*264 + c]) = pk;
  }
  __syncthreads();

  // P1: gi = U@Mih^T (waves 0-3), gh = slots@Whh^T (waves 4-7); N=768, K=256 each.
  // 12 col-tiles per wave, double-buffered B fragments streamed from L2.
  {
    const unsigned short* W = (wv < 4) ? Mih : Whh;
    const unsigned short* As = (wv < 4) ? A1 : SBf;
    float* G = (wv < 4) ? G1 : G2;
    int w4 = wv & 3;
    bf16x8 af[8];
    #pragma unroll
    for(int k = 0; k < 8; k++) af[k] = *(const bf16x8*)(&As[lm*264 + k*32 + lg*8]);
    const unsigned short* brow = W + ((size_t)(w4*192 + lm))*CD + lg*8;
    bf16x8 bv[8], bw[8];
    #pragma unroll
    for(int k = 0; k < 8; k++) bv[k] = *(const bf16x8*)(brow + k*32);
    for(int t = 0; t < 12; t++){
      if(t < 11){
        const unsigned short* bn = brow + (size_t)(t + 1)*16*CD;
        #pragma unroll
        for(int k = 0; k < 8; k++) bw[k] = *(const bf16x8*)(bn + k*32);
      }
      f32x4 acc = {0.f,0.f,0.f,0.f};
      #pragma unroll
      for(int k = 0; k < 8; k++) acc = mfma16(af[k], bv[k], acc);
      if(lg < 2){
        int cb = w4*192 + t*16 + lm;
        #pragma unroll
        for(int reg = 0; reg < 4; reg++) G[(lg*4 + reg)*777 + cb] = acc[reg];
      }
      #pragma unroll
      for(int k = 0; k < 8; k++) bv[k] = bw[k];
    }
  }
  __syncthreads();

  // P2: GRU gate activations + LN(mlp) -> A1 (bf16 lnh); one wave per slot row
  {
    int r = wv;
    float dsum = dpart[((size_t)(l & 15)*CB + b)*CS + r];
    #pragma unroll
    for(int m = 1; m < 16; m <<= 1) dsum += __shfl_xor(dsum, m);
    float invd = 1.0f / dsum;
    const float* srow = slots + ((size_t)b*CS + r)*CD;
    float hv[4]; float s1 = 0.f, s2 = 0.f;
    #pragma unroll
    for(int i = 0; i < 4; i++){
      int c = l + 64*i;
      float gr = G1[r*777 + c]*invd + bih[c] + G2[r*777 + c] + bhh[c];
      float gz = G1[r*777 + 256 + c]*invd + bih[256 + c] + G2[r*777 + 256 + c] + bhh[256 + c];
      float gn = G1[r*777 + 512 + c]*invd + bih[512 + c];
      float hn = G2[r*777 + 512 + c] + bhh[512 + c];
      float rr = 1.0f/(1.0f + __expf(-gr));
      float zz = 1.0f/(1.0f + __expf(-gz));
      float nn = tanhf(gn + rr*hn);
      float h = (1.0f - zz)*nn + zz*srow[c];
      hv[i] = h; Hh[r*257 + c] = h; s1 += h; s2 += h*h;
    }
    #pragma unroll
    for(int m = 1; m < 64; m <<= 1){ s1 += __shfl_xor(s1, m); s2 += __shfl_xor(s2, m); }
    float mean = s1 * (1.0f/CD);
    float var  = fmaxf(s2 * (1.0f/CD) - mean*mean, 0.0f);
    float rstd = rsqrtf(var + 1e-5f);
    #pragma unroll
    for(int i = 0; i < 4; i++){
      int c = l + 64*i;
      A1[r*264 + c] = f2bf((hv[i] - mean)*rstd*lmw[c] + lmb[c]);
    }
  }
  __syncthreads();

  // P3: h1 = relu(lnh@w1^T + b1) -> A3 bf16   (N=512, K=256; 4 col-tiles per wave)
  {
    bf16x8 af[8];
    #pragma unroll
    for(int k = 0; k < 8; k++) af[k] = *(const bf16x8*)(&A1[lm*264 + k*32 + lg*8]);
    const unsigned short* brow = w1b + ((size_t)(wv*64 + lm))*CD + lg*8;
    for(int t = 0; t < 4; t++){
      const unsigned short* bn = brow + (size_t)t*16*CD;
      f32x4 acc = {0.f,0.f,0.f,0.f};
      #pragma unroll
      for(int k = 0; k < 8; k++){
        bf16x8 bv = *(const bf16x8*)(bn + k*32);
        acc = mfma16(af[k], bv, acc);
      }
      if(lg < 2){
        int c = wv*64 + t*16 + lm;
        float bb = b1[c];
        #pragma unroll
        for(int reg = 0; reg < 4; reg++)
          A3[(lg*4 + reg)*520 + c] = f2bf(fmaxf(acc[reg] + bb, 0.0f));
      }
    }
  }
  __syncthreads();

  // P4: out = h1@w2^T + b2 + Hh   (N=256, K=512; 2 col-tiles per wave)
  {
    bf16x8 af[16];
    #pragma unroll
    for(int k = 0; k < 16; k++) af[k] = *(const bf16x8*)(&A3[lm*520 + k*32 + lg*8]);
    const unsigned short* brow = w2b + ((size_t)(wv*32 + lm))*CH + lg*8;
    for(int t = 0; t < 2; t++){
      const unsigned short* bn = brow + (size_t)t*16*CH;
      f32x4 acc = {0.f,0.f,0.f,0.f};
      #pragma unroll
      for(int k = 0; k < 16; k++){
        bf16x8 bv = *(const bf16x8*)(bn + k*32);
        acc = mfma16(af[k], bv, acc);
      }
      if(lg < 2){
        int c = wv*32 + t*16 + lm;
        float bb = b2[c];
        #pragma unroll
        for(int reg = 0; reg < 4; reg++){
          int row = lg*4 + reg;
          out[((size_t)b*CS + row)*CD + c] = acc[reg] + bb + Hh[row*257 + c];
        }
      }
    }
  }
}

extern "C" void kernel_launch(void* const* d_in, const int* in_sizes, int n_in,
                              void* d_out, int out_size, void* d_ws, size_t ws_size,
                              hipStream_t stream){
  const float* inputs = (const float*)d_in[0];
  const float* noise  = (const float*)d_in[1];
  const float* ln_in_w = (const float*)d_in[2];
  const float* ln_in_b = (const float*)d_in[3];
  const float* ln_sl_w = (const float*)d_in[4];
  const float* ln_sl_b = (const float*)d_in[5];
  const float* ln_ml_w = (const float*)d_in[6];
  const float* ln_ml_b = (const float*)d_in[7];
  const float* mu   = (const float*)d_in[8];
  const float* lsig = (const float*)d_in[9];
  const float* Wq  = (const float*)d_in[10];
  const float* Wk  = (const float*)d_in[11];
  const float* Wv  = (const float*)d_in[12];
  const float* wih = (const float*)d_in[13];
  const float* whh = (const float*)d_in[14];
  const float* bih = (const float*)d_in[15];
  const float* bhh = (const float*)d_in[16];
  const float* w1  = (const float*)d_in[17];
  const float* b1  = (const float*)d_in[18];
  const float* w2  = (const float*)d_in[19];
  const float* b2  = (const float*)d_in[20];

  char* ws = (char*)d_ws;
  size_t off = 0;
  unsigned short* x = (unsigned short*)(ws + off); off += (size_t)CB*CN*CD*2;
  float* slots = (float*)(ws + off); off += (size_t)CB*CS*CD*4;
  float* Upart = (float*)(ws + off); off += (size_t)16*CB*CS*CD*4;
  float* dpart = (float*)(ws + off); off += (size_t)16*CB*CS*4;
  unsigned short* M1T    = (unsigned short*)(ws + off); off += (size_t)CD*CD*2;
  unsigned short* Mih_bf = (unsigned short*)(ws + off); off += (size_t)768*CD*2;
  unsigned short* Whh_bf = (unsigned short*)(ws + off); off += (size_t)768*CD*2;
  unsigned short* w1_bf  = (unsigned short*)(ws + off); off += (size_t)CH*CD*2;
  unsigned short* w2_bf  = (unsigned short*)(ws + off); off += (size_t)CD*CH*2;

  k_ln<<<4096, 256, 0, stream>>>(inputs, ln_in_w, ln_in_b, x);
  k_setup<<<3328, 256, 0, stream>>>(Wq, Wk, wih, Wv, whh, w1, w2, noise, mu, lsig,
                                    M1T, Mih_bf, Whh_bf, w1_bf, w2_bf, slots);

  for(int it = 0; it < 3; it++){
    k_attn<<<1024, 256, 0, stream>>>(x, slots, ln_sl_w, ln_sl_b, M1T, Upart, dpart);
    float* dst = (it == 2) ? (float*)d_out : slots;
    k_update<<<64, 512, 0, stream>>>(Upart, slots, dpart,
        Mih_bf, Whh_bf, w1_bf, w2_bf,
        bih, bhh, ln_ml_w, ln_ml_b, b1, b2, dst);
  }
}